// Round 1
// baseline (201.198 us; speedup 1.0000x reference)
//
#include <hip/hip_runtime.h>

#define LSZ 512
#define CCH 4
#define NLAY 4
#define TILE 64
#define HALO 8
#define RG 80        // region size = TILE + 2*HALO
#define RG2 40       // float2 row pitch

__device__ __forceinline__ float celuf(float y) {
    return y >= 0.0f ? y : __expf(y) - 1.0f;
}

// One workgroup per (b, c, upper-triangular 64x64 tile).
// Builds g from n on the fly (never materialized in HBM), runs all 4 stencil
// layers in LDS ping-pong buffers with halo 8, then reduces the 127 cyclic
// diagonals of the 64x64 core into sep via global atomics.
// Symmetry: x stays bitwise-symmetric (sums grouped (l+r)+(u+d)), so tiles with
// ti>tj are skipped and off-diagonal tiles credit both bin r and bin (512-r).
__global__ __launch_bounds__(256) void stencil_kernel(
    const float* __restrict__ nn,
    const float* __restrict__ w_self,
    const float* __restrict__ w_nbr,
    float* __restrict__ sep)
{
    __shared__ __align__(16) float bufA[RG * RG];
    __shared__ __align__(16) float bufB[RG * RG];
    __shared__ float nrow[RG][3];
    __shared__ float ncol[RG][3];

    const int tid = threadIdx.x;
    const int bid = blockIdx.x;
    const int img = bid / 36;           // 36 upper-tri tiles per (b,c) image
    int t = bid - img * 36;
    const int b = img >> 2;
    const int c = img & 3;
    int ti = 0;
    while (t >= 8 - ti) { t -= 8 - ti; ti++; }
    const int tj = ti + t;
    const int gi0 = ti * TILE;
    const int gj0 = tj * TILE;
    const int dd = (gj0 - gi0) & (LSZ - 1);   // diag when (i-j-dd) % 512 == 0

    // ---- load n rows & cols (with halo, cyclic wrap) ----
    for (int u = tid; u < RG * 3 * 2; u += 256) {
        int which = u >= RG * 3;
        int v = which ? u - RG * 3 : u;
        int rr = v / 3, d = v - 3 * rr;
        int base = which ? gj0 : gi0;
        int gl = (base - HALO + rr) & (LSZ - 1);
        float val = nn[(b * LSZ + gl) * 3 + d];
        if (which) ncol[rr][d] = val; else nrow[rr][d] = val;
    }
    __syncthreads();

    // ---- build g (Gram matrix, zero diagonal) into bufA, 2x2 blocks ----
    for (int g = tid; g < 1600; g += 256) {
        int gi2 = g / RG2;
        int gj2 = g - RG2 * gi2;
        int i = 2 * gi2, j = 2 * gj2;
        float a00 = nrow[i][0],   a01 = nrow[i][1],   a02 = nrow[i][2];
        float a10 = nrow[i+1][0], a11 = nrow[i+1][1], a12 = nrow[i+1][2];
        float c00 = ncol[j][0],   c01 = ncol[j][1],   c02 = ncol[j][2];
        float c10 = ncol[j+1][0], c11 = ncol[j+1][1], c12 = ncol[j+1][2];
        float g00 = a00*c00 + a01*c01 + a02*c02;
        float g01 = a00*c10 + a01*c11 + a02*c12;
        float g10 = a10*c00 + a11*c01 + a12*c02;
        float g11 = a10*c10 + a11*c11 + a12*c12;
        int e = i - j - dd;
        if (((e)   & 511) == 0) { g00 = 0.0f; g11 = 0.0f; }
        if (((e-1) & 511) == 0)   g01 = 0.0f;
        if (((e+1) & 511) == 0)   g10 = 0.0f;
        *(float2*)&bufA[i * RG + j]     = make_float2(g00, g01);
        *(float2*)&bufA[(i+1) * RG + j] = make_float2(g10, g11);
    }
    __syncthreads();

    // ---- 4 stencil layers, ping-pong, region shrinks by 2/side per layer ----
    float* src = bufA;
    float* dst = bufB;
    for (int ell = 0; ell < NLAY; ell++) {
        const float ws  = w_self[c * NLAY + ell];
        const float wn1 = w_nbr[(c * NLAY + ell) * 2 + 0];
        const float wn2 = w_nbr[(c * NLAY + ell) * 2 + 1];
        const int pad = 2 * (ell + 1);
        const float2* s2 = (const float2*)src;
        float2* d2 = (float2*)dst;
        for (int g = tid; g < 1600; g += 256) {
            int gi2 = g / RG2;
            int gj2 = g - RG2 * gi2;
            int i = 2 * gi2, j = 2 * gj2;
            if (i < pad || i > 78 - pad || j < pad || j > 78 - pad) continue;
            float2 vm2 = s2[(i-2)*RG2 + gj2];
            float2 vm1 = s2[(i-1)*RG2 + gj2];
            float2 v0  = s2[(i  )*RG2 + gj2];
            float2 vp1 = s2[(i+1)*RG2 + gj2];
            float2 vp2 = s2[(i+2)*RG2 + gj2];
            float2 vp3 = s2[(i+3)*RG2 + gj2];
            float2 h0m = s2[(i  )*RG2 + gj2 - 1];
            float2 h0p = s2[(i  )*RG2 + gj2 + 1];
            float2 h1m = s2[(i+1)*RG2 + gj2 - 1];
            float2 h1p = s2[(i+1)*RG2 + gj2 + 1];
            // group (left+right)+(up+down) so transpose positions are bitwise equal
            float y00 = ws*v0.x  + wn1*((h0m.y + v0.y ) + (vm1.x + vp1.x))
                                 + wn2*((h0m.x + h0p.x) + (vm2.x + vp2.x));
            float y01 = ws*v0.y  + wn1*((v0.x  + h0p.x) + (vm1.y + vp1.y))
                                 + wn2*((h0m.y + h0p.y) + (vm2.y + vp2.y));
            float y10 = ws*vp1.x + wn1*((h1m.y + vp1.y) + (v0.x  + vp2.x))
                                 + wn2*((h1m.x + h1p.x) + (vm1.x + vp3.x));
            float y11 = ws*vp1.y + wn1*((vp1.x + h1p.x) + (v0.y  + vp2.y))
                                 + wn2*((h1m.y + h1p.y) + (vm1.y + vp3.y));
            float x00 = v0.x  + celuf(y00);
            float x01 = v0.y  + celuf(y01);
            float x10 = vp1.x + celuf(y10);
            float x11 = vp1.y + celuf(y11);
            int e = i - j - dd;
            if (((e)   & 511) == 0) { x00 = 0.0f; x11 = 0.0f; }
            if (((e-1) & 511) == 0)   x01 = 0.0f;
            if (((e+1) & 511) == 0)   x10 = 0.0f;
            d2[(i  )*RG2 + gj2] = make_float2(x00, x01);
            d2[(i+1)*RG2 + gj2] = make_float2(x10, x11);
        }
        __syncthreads();
        float* tmp = src; src = dst; dst = tmp;
    }
    // final x is in src (core = region [8,72)^2)

    // ---- cyclic-diagonal reduction: 127 diagonals, 2 threads each ----
    if (tid < 254) {
        int dt = tid >> 1;
        int half = tid & 1;
        int delta = dt - 63;                 // j - i in [-63, 63]
        int ad = delta < 0 ? -delta : delta;
        int Nd = 64 - ad;
        int i0 = 8 + (delta < 0 ? -delta : 0);
        int base = i0 * RG + (i0 + delta);
        float s = 0.0f;
        for (int k = half; k < Nd; k += 2)
            s += src[base + k * (RG + 1)];
        s += __shfl_xor(s, 1);
        if (half == 0) {
            int r = (gj0 - gi0 + delta) & (LSZ - 1);
            float* sp = sep + (b * CCH + c) * LSZ;
            atomicAdd(sp + r, s);
            if (ti != tj)  // mirror contribution for the skipped transpose tile
                atomicAdd(sp + ((LSZ - r) & (LSZ - 1)), s);
        }
    }
}

// MLP head: one block per batch element, thread k owns hidden unit k.
// Double accumulation: y ~ 26.7 and we need |dy| <= 0.02 for the 2% threshold.
__global__ __launch_bounds__(256) void mlp_kernel(
    const float* __restrict__ sep,
    const float* __restrict__ W1,
    const float* __restrict__ b1,
    const float* __restrict__ W2,
    const float* __restrict__ b2,
    float* __restrict__ out)
{
    __shared__ float sv[2048];
    __shared__ double red[4];
    const int b = blockIdx.x;
    const int k = threadIdx.x;
    for (int m = k; m < 2048; m += 256) sv[m] = sep[b * 2048 + m];
    __syncthreads();
    double a0 = 0, a1 = 0, a2 = 0, a3 = 0;
    const float* w = W1 + k;
    for (int m = 0; m < 2048; m += 4) {
        a0 += (double)sv[m]     * (double)w[(m)     * 256];
        a1 += (double)sv[m + 1] * (double)w[(m + 1) * 256];
        a2 += (double)sv[m + 2] * (double)w[(m + 2) * 256];
        a3 += (double)sv[m + 3] * (double)w[(m + 3) * 256];
    }
    double h = ((a0 + a1) + (a2 + a3)) + (double)b1[k];
    h = h >= 0.0 ? h : exp(h) - 1.0;          // celu
    double p = h * (double)W2[k];
    for (int off = 32; off >= 1; off >>= 1) p += __shfl_down(p, off);
    if ((k & 63) == 0) red[k >> 6] = p;
    __syncthreads();
    if (k == 0) {
        double y = ((red[0] + red[1]) + (red[2] + red[3])) + (double)b2[0];
        out[b] = (float)exp(-y);
    }
}

extern "C" void kernel_launch(void* const* d_in, const int* in_sizes, int n_in,
                              void* d_out, int out_size, void* d_ws, size_t ws_size,
                              hipStream_t stream) {
    const float* nn     = (const float*)d_in[0];
    const float* w_self = (const float*)d_in[1];
    const float* w_nbr  = (const float*)d_in[2];
    const float* W1     = (const float*)d_in[3];
    const float* b1     = (const float*)d_in[4];
    const float* W2     = (const float*)d_in[5];
    const float* b2     = (const float*)d_in[6];
    float* out = (float*)d_out;
    float* sep = (float*)d_ws;   // (B, C, L) fp32 = 128 KB scratch

    hipMemsetAsync(sep, 0, 16 * CCH * LSZ * sizeof(float), stream);
    stencil_kernel<<<64 * 36, 256, 0, stream>>>(nn, w_self, w_nbr, sep);
    mlp_kernel<<<16, 256, 0, stream>>>(sep, W1, b1, W2, b2, out);
}

// Round 2
// 131.999 us; speedup vs baseline: 1.5242x; 1.5242x over previous
//
#include <hip/hip_runtime.h>

#define LSZ 512
#define CCH 4
#define NLAY 4
#define TILE 64
#define HALO 8
#define RG 80        // region size = TILE + 2*HALO
#define RG2 40       // float2 row pitch

__device__ __forceinline__ float celuf(float y) {
    return y >= 0.0f ? y : __expf(y) - 1.0f;
}

// One workgroup per (b, c, upper-triangular 64x64 tile).
// Builds g from n on the fly (never materialized in HBM), runs all 4 stencil
// layers in LDS ping-pong buffers with halo 8, then reduces the 127 cyclic
// diagonals of the 64x64 core into sep via global atomics.
// Symmetry: x stays bitwise-symmetric (sums grouped (l+r)+(u+d)), so tiles with
// ti>tj are skipped and off-diagonal tiles credit both bin r and bin (512-r).
__global__ __launch_bounds__(256) void stencil_kernel(
    const float* __restrict__ nn,
    const float* __restrict__ w_self,
    const float* __restrict__ w_nbr,
    float* __restrict__ sep)
{
    __shared__ __align__(16) float bufA[RG * RG];
    __shared__ __align__(16) float bufB[RG * RG];
    __shared__ float nrow[RG][3];
    __shared__ float ncol[RG][3];

    const int tid = threadIdx.x;
    const int bid = blockIdx.x;
    const int img = bid / 36;           // 36 upper-tri tiles per (b,c) image
    int t = bid - img * 36;
    const int b = img >> 2;
    const int c = img & 3;
    int ti = 0;
    while (t >= 8 - ti) { t -= 8 - ti; ti++; }
    const int tj = ti + t;
    const int gi0 = ti * TILE;
    const int gj0 = tj * TILE;
    const int dd = (gj0 - gi0) & (LSZ - 1);   // diag when (i-j-dd) % 512 == 0

    // ---- load n rows & cols (with halo, cyclic wrap) ----
    for (int u = tid; u < RG * 3 * 2; u += 256) {
        int which = u >= RG * 3;
        int v = which ? u - RG * 3 : u;
        int rr = v / 3, d = v - 3 * rr;
        int base = which ? gj0 : gi0;
        int gl = (base - HALO + rr) & (LSZ - 1);
        float val = nn[(b * LSZ + gl) * 3 + d];
        if (which) ncol[rr][d] = val; else nrow[rr][d] = val;
    }
    __syncthreads();

    // ---- build g (Gram matrix, zero diagonal) into bufA, 2x2 blocks ----
    for (int g = tid; g < 1600; g += 256) {
        int gi2 = g / RG2;
        int gj2 = g - RG2 * gi2;
        int i = 2 * gi2, j = 2 * gj2;
        float a00 = nrow[i][0],   a01 = nrow[i][1],   a02 = nrow[i][2];
        float a10 = nrow[i+1][0], a11 = nrow[i+1][1], a12 = nrow[i+1][2];
        float c00 = ncol[j][0],   c01 = ncol[j][1],   c02 = ncol[j][2];
        float c10 = ncol[j+1][0], c11 = ncol[j+1][1], c12 = ncol[j+1][2];
        float g00 = a00*c00 + a01*c01 + a02*c02;
        float g01 = a00*c10 + a01*c11 + a02*c12;
        float g10 = a10*c00 + a11*c01 + a12*c02;
        float g11 = a10*c10 + a11*c11 + a12*c12;
        int e = i - j - dd;
        if (((e)   & 511) == 0) { g00 = 0.0f; g11 = 0.0f; }
        if (((e-1) & 511) == 0)   g01 = 0.0f;
        if (((e+1) & 511) == 0)   g10 = 0.0f;
        *(float2*)&bufA[i * RG + j]     = make_float2(g00, g01);
        *(float2*)&bufA[(i+1) * RG + j] = make_float2(g10, g11);
    }
    __syncthreads();

    // ---- 4 stencil layers, ping-pong, region shrinks by 2/side per layer ----
    float* src = bufA;
    float* dst = bufB;
    for (int ell = 0; ell < NLAY; ell++) {
        const float ws  = w_self[c * NLAY + ell];
        const float wn1 = w_nbr[(c * NLAY + ell) * 2 + 0];
        const float wn2 = w_nbr[(c * NLAY + ell) * 2 + 1];
        const int pad = 2 * (ell + 1);
        const float2* s2 = (const float2*)src;
        float2* d2 = (float2*)dst;
        for (int g = tid; g < 1600; g += 256) {
            int gi2 = g / RG2;
            int gj2 = g - RG2 * gi2;
            int i = 2 * gi2, j = 2 * gj2;
            if (i < pad || i > 78 - pad || j < pad || j > 78 - pad) continue;
            float2 vm2 = s2[(i-2)*RG2 + gj2];
            float2 vm1 = s2[(i-1)*RG2 + gj2];
            float2 v0  = s2[(i  )*RG2 + gj2];
            float2 vp1 = s2[(i+1)*RG2 + gj2];
            float2 vp2 = s2[(i+2)*RG2 + gj2];
            float2 vp3 = s2[(i+3)*RG2 + gj2];
            float2 h0m = s2[(i  )*RG2 + gj2 - 1];
            float2 h0p = s2[(i  )*RG2 + gj2 + 1];
            float2 h1m = s2[(i+1)*RG2 + gj2 - 1];
            float2 h1p = s2[(i+1)*RG2 + gj2 + 1];
            // group (left+right)+(up+down) so transpose positions are bitwise equal
            float y00 = ws*v0.x  + wn1*((h0m.y + v0.y ) + (vm1.x + vp1.x))
                                 + wn2*((h0m.x + h0p.x) + (vm2.x + vp2.x));
            float y01 = ws*v0.y  + wn1*((v0.x  + h0p.x) + (vm1.y + vp1.y))
                                 + wn2*((h0m.y + h0p.y) + (vm2.y + vp2.y));
            float y10 = ws*vp1.x + wn1*((h1m.y + vp1.y) + (v0.x  + vp2.x))
                                 + wn2*((h1m.x + h1p.x) + (vm1.x + vp3.x));
            float y11 = ws*vp1.y + wn1*((vp1.x + h1p.x) + (v0.y  + vp2.y))
                                 + wn2*((h1m.y + h1p.y) + (vm1.y + vp3.y));
            float x00 = v0.x  + celuf(y00);
            float x01 = v0.y  + celuf(y01);
            float x10 = vp1.x + celuf(y10);
            float x11 = vp1.y + celuf(y11);
            int e = i - j - dd;
            if (((e)   & 511) == 0) { x00 = 0.0f; x11 = 0.0f; }
            if (((e-1) & 511) == 0)   x01 = 0.0f;
            if (((e+1) & 511) == 0)   x10 = 0.0f;
            d2[(i  )*RG2 + gj2] = make_float2(x00, x01);
            d2[(i+1)*RG2 + gj2] = make_float2(x10, x11);
        }
        __syncthreads();
        float* tmp = src; src = dst; dst = tmp;
    }
    // final x is in src (core = region [8,72)^2)

    // ---- cyclic-diagonal reduction: 127 diagonals, 2 threads each ----
    if (tid < 254) {
        int dt = tid >> 1;
        int half = tid & 1;
        int delta = dt - 63;                 // j - i in [-63, 63]
        int ad = delta < 0 ? -delta : delta;
        int Nd = 64 - ad;
        int i0 = 8 + (delta < 0 ? -delta : 0);
        int base = i0 * RG + (i0 + delta);
        float s = 0.0f;
        for (int k = half; k < Nd; k += 2)
            s += src[base + k * (RG + 1)];
        s += __shfl_xor(s, 1);
        if (half == 0) {
            int r = (gj0 - gi0 + delta) & (LSZ - 1);
            float* sp = sep + (b * CCH + c) * LSZ;
            atomicAdd(sp + r, s);
            if (ti != tj)  // mirror contribution for the skipped transpose tile
                atomicAdd(sp + ((LSZ - r) & (LSZ - 1)), s);
        }
    }
}

// MLP stage 1: h[b][k] = celu(sep[b,:] . W1[:,k] + b1[k]) in double.
// 128 blocks = 16 b x 8 k-groups; 256 threads = 32 k x 8 m-partitions.
// Consecutive lanes read consecutive W1 columns (coalesced 128B segments).
__global__ __launch_bounds__(256) void mlp1_kernel(
    const float* __restrict__ sep,
    const float* __restrict__ W1,
    const float* __restrict__ b1,
    double* __restrict__ h)
{
    __shared__ float sv[2048];
    __shared__ double red[256];
    const int b   = blockIdx.x >> 3;
    const int kg  = blockIdx.x & 7;
    const int tid = threadIdx.x;
    const int kl  = tid & 31;        // hidden unit within group
    const int mp  = tid >> 5;        // m-partition 0..7
    for (int m = tid; m < 2048; m += 256) sv[m] = sep[b * 2048 + m];
    __syncthreads();
    const int k = kg * 32 + kl;
    const float* w = W1 + k;
    double a0 = 0, a1 = 0, a2 = 0, a3 = 0;
    const int m0 = mp * 256;
    for (int m = m0; m < m0 + 256; m += 4) {
        a0 += (double)sv[m]     * (double)w[(m)     * 256];
        a1 += (double)sv[m + 1] * (double)w[(m + 1) * 256];
        a2 += (double)sv[m + 2] * (double)w[(m + 2) * 256];
        a3 += (double)sv[m + 3] * (double)w[(m + 3) * 256];
    }
    red[tid] = ((a0 + a1) + (a2 + a3));
    __syncthreads();
    if (tid < 32) {
        double s = 0;
        for (int p = 0; p < 8; p++) s += red[kl + 32 * p];
        s += (double)b1[k];
        s = s >= 0.0 ? s : exp(s) - 1.0;      // celu
        h[b * 256 + k] = s;
    }
}

// MLP stage 2: y[b] = h[b,:] . W2 + b2 ; out[b] = exp(-y)
__global__ __launch_bounds__(64) void mlp2_kernel(
    const double* __restrict__ h,
    const float* __restrict__ W2,
    const float* __restrict__ b2,
    float* __restrict__ out)
{
    const int b = blockIdx.x;
    const int t = threadIdx.x;
    double p = 0;
    for (int j = 0; j < 4; j++) {
        int k = t * 4 + j;
        p += h[b * 256 + k] * (double)W2[k];
    }
    for (int off = 32; off >= 1; off >>= 1) p += __shfl_down(p, off);
    if (t == 0) out[b] = (float)exp(-(p + (double)b2[0]));
}

extern "C" void kernel_launch(void* const* d_in, const int* in_sizes, int n_in,
                              void* d_out, int out_size, void* d_ws, size_t ws_size,
                              hipStream_t stream) {
    const float* nn     = (const float*)d_in[0];
    const float* w_self = (const float*)d_in[1];
    const float* w_nbr  = (const float*)d_in[2];
    const float* W1     = (const float*)d_in[3];
    const float* b1     = (const float*)d_in[4];
    const float* W2     = (const float*)d_in[5];
    const float* b2     = (const float*)d_in[6];
    float* out = (float*)d_out;
    float* sep = (float*)d_ws;                      // (B, C, L) fp32 = 128 KB
    double* h  = (double*)((char*)d_ws + 16 * CCH * LSZ * sizeof(float)); // 32 KB

    hipMemsetAsync(sep, 0, 16 * CCH * LSZ * sizeof(float), stream);
    stencil_kernel<<<64 * 36, 256, 0, stream>>>(nn, w_self, w_nbr, sep);
    mlp1_kernel<<<128, 256, 0, stream>>>(sep, W1, b1, h);
    mlp2_kernel<<<16, 64, 0, stream>>>(h, W2, b2, out);
}

// Round 3
// 113.972 us; speedup vs baseline: 1.7653x; 1.1582x over previous
//
#include <hip/hip_runtime.h>

#define LSZ 512
#define CCH 4
#define NLAY 4
#define TILE 64
#define HALO 8
#define RG 80        // region size = TILE + 2*HALO
#define RG2 40       // float2 row pitch

__device__ __forceinline__ float celuf(float y) {
    return y >= 0.0f ? y : __expf(y) - 1.0f;
}

// One workgroup per (b, c, upper-triangular 64x64 tile).
// Builds g from n on the fly (never in HBM), runs 4 stencil layers IN PLACE in
// a single 80x80 LDS buffer (outputs staged in registers between two barriers),
// then reduces the 127 cyclic diagonals of the 64x64 core into sep via atomics.
// Symmetry: x stays bitwise-symmetric (sums grouped (l+r)+(u+d)), so tiles with
// ti>tj are skipped and off-diagonal tiles credit both bin r and bin (512-r).
// LDS 27.5 KB -> 4-5 blocks/CU (was 53 KB -> 3).
__global__ __launch_bounds__(256, 4) void stencil_kernel(
    const float* __restrict__ nn,
    const float* __restrict__ w_self,
    const float* __restrict__ w_nbr,
    float* __restrict__ sep)
{
    __shared__ __align__(16) float buf[RG * RG];
    __shared__ float nrow[RG][3];
    __shared__ float ncol[RG][3];

    const int tid = threadIdx.x;
    const int bid = blockIdx.x;
    const int img = bid / 36;           // 36 upper-tri tiles per (b,c) image
    int t = bid - img * 36;
    const int b = img >> 2;
    const int c = img & 3;
    int ti = 0;
    while (t >= 8 - ti) { t -= 8 - ti; ti++; }
    const int tj = ti + t;
    const int gi0 = ti * TILE;
    const int gj0 = tj * TILE;
    const int dd = (gj0 - gi0) & (LSZ - 1);   // diag when (i-j-dd) % 512 == 0

    // ---- load n rows & cols (with halo, cyclic wrap) ----
    for (int u = tid; u < RG * 3 * 2; u += 256) {
        int which = u >= RG * 3;
        int v = which ? u - RG * 3 : u;
        int rr = v / 3, d = v - 3 * rr;
        int base = which ? gj0 : gi0;
        int gl = (base - HALO + rr) & (LSZ - 1);
        float val = nn[(b * LSZ + gl) * 3 + d];
        if (which) ncol[rr][d] = val; else nrow[rr][d] = val;
    }

    // ---- per-thread site indices (2x2 blocks), fixed across layers ----
    int ii[7], jj[7];
#pragma unroll
    for (int it = 0; it < 7; it++) {
        int g = tid + 256 * it;
        if (g < 1600) {
            int gi2 = g / RG2;
            ii[it] = 2 * gi2;
            jj[it] = 2 * (g - RG2 * gi2);
        } else { ii[it] = -100; jj[it] = 0; }
    }
    __syncthreads();

    // ---- build g (Gram matrix, zero diagonal), 2x2 blocks ----
#pragma unroll
    for (int it = 0; it < 7; it++) {
        int i = ii[it], j = jj[it];
        if (i < 0) continue;
        float a00 = nrow[i][0],   a01 = nrow[i][1],   a02 = nrow[i][2];
        float a10 = nrow[i+1][0], a11 = nrow[i+1][1], a12 = nrow[i+1][2];
        float c00 = ncol[j][0],   c01 = ncol[j][1],   c02 = ncol[j][2];
        float c10 = ncol[j+1][0], c11 = ncol[j+1][1], c12 = ncol[j+1][2];
        float g00 = a00*c00 + a01*c01 + a02*c02;
        float g01 = a00*c10 + a01*c11 + a02*c12;
        float g10 = a10*c00 + a11*c01 + a12*c02;
        float g11 = a10*c10 + a11*c11 + a12*c12;
        int e = i - j - dd;
        if (((e)   & 511) == 0) { g00 = 0.0f; g11 = 0.0f; }
        if (((e-1) & 511) == 0)   g01 = 0.0f;
        if (((e+1) & 511) == 0)   g10 = 0.0f;
        *(float2*)&buf[i * RG + j]     = make_float2(g00, g01);
        *(float2*)&buf[(i+1) * RG + j] = make_float2(g10, g11);
    }
    __syncthreads();

    // ---- 4 stencil layers, in place: compute->regs, barrier, write, barrier ----
    const float2* s2 = (const float2*)buf;
    float2* d2 = (float2*)buf;
    for (int ell = 0; ell < NLAY; ell++) {
        const float ws  = w_self[c * NLAY + ell];
        const float wn1 = w_nbr[(c * NLAY + ell) * 2 + 0];
        const float wn2 = w_nbr[(c * NLAY + ell) * 2 + 1];
        const int pad = 2 * (ell + 1);
        float2 o0[7], o1[7];
#pragma unroll
        for (int it = 0; it < 7; it++) {
            int i = ii[it], j = jj[it];
            if (i < pad || i > 78 - pad || j < pad || j > 78 - pad) continue;
            int gj2 = j >> 1;
            float2 vm2 = s2[(i-2)*RG2 + gj2];
            float2 vm1 = s2[(i-1)*RG2 + gj2];
            float2 v0  = s2[(i  )*RG2 + gj2];
            float2 vp1 = s2[(i+1)*RG2 + gj2];
            float2 vp2 = s2[(i+2)*RG2 + gj2];
            float2 vp3 = s2[(i+3)*RG2 + gj2];
            float2 h0m = s2[(i  )*RG2 + gj2 - 1];
            float2 h0p = s2[(i  )*RG2 + gj2 + 1];
            float2 h1m = s2[(i+1)*RG2 + gj2 - 1];
            float2 h1p = s2[(i+1)*RG2 + gj2 + 1];
            // group (left+right)+(up+down) so transpose positions are bitwise equal
            float y00 = ws*v0.x  + wn1*((h0m.y + v0.y ) + (vm1.x + vp1.x))
                                 + wn2*((h0m.x + h0p.x) + (vm2.x + vp2.x));
            float y01 = ws*v0.y  + wn1*((v0.x  + h0p.x) + (vm1.y + vp1.y))
                                 + wn2*((h0m.y + h0p.y) + (vm2.y + vp2.y));
            float y10 = ws*vp1.x + wn1*((h1m.y + vp1.y) + (v0.x  + vp2.x))
                                 + wn2*((h1m.x + h1p.x) + (vm1.x + vp3.x));
            float y11 = ws*vp1.y + wn1*((vp1.x + h1p.x) + (v0.y  + vp2.y))
                                 + wn2*((h1m.y + h1p.y) + (vm1.y + vp3.y));
            float x00 = v0.x  + celuf(y00);
            float x01 = v0.y  + celuf(y01);
            float x10 = vp1.x + celuf(y10);
            float x11 = vp1.y + celuf(y11);
            int e = i - j - dd;
            if (((e)   & 511) == 0) { x00 = 0.0f; x11 = 0.0f; }
            if (((e-1) & 511) == 0)   x01 = 0.0f;
            if (((e+1) & 511) == 0)   x10 = 0.0f;
            o0[it] = make_float2(x00, x01);
            o1[it] = make_float2(x10, x11);
        }
        __syncthreads();
#pragma unroll
        for (int it = 0; it < 7; it++) {
            int i = ii[it], j = jj[it];
            if (i < pad || i > 78 - pad || j < pad || j > 78 - pad) continue;
            int gj2 = j >> 1;
            d2[(i  )*RG2 + gj2] = o0[it];
            d2[(i+1)*RG2 + gj2] = o1[it];
        }
        __syncthreads();
    }
    // final x is in buf (core = region [8,72)^2)

    // ---- cyclic-diagonal reduction: 127 diagonals, 2 threads each ----
    if (tid < 254) {
        int dt = tid >> 1;
        int half = tid & 1;
        int delta = dt - 63;                 // j - i in [-63, 63]
        int ad = delta < 0 ? -delta : delta;
        int Nd = 64 - ad;
        int i0 = 8 + (delta < 0 ? -delta : 0);
        int base = i0 * RG + (i0 + delta);
        float s = 0.0f;
        for (int k = half; k < Nd; k += 2)
            s += buf[base + k * (RG + 1)];
        s += __shfl_xor(s, 1);
        if (half == 0) {
            int r = (gj0 - gi0 + delta) & (LSZ - 1);
            float* sp = sep + (b * CCH + c) * LSZ;
            atomicAdd(sp + r, s);
            if (ti != tj)  // mirror contribution for the skipped transpose tile
                atomicAdd(sp + ((LSZ - r) & (LSZ - 1)), s);
        }
    }
}

// MLP stage 1: partial[b][mp][k] = sep[b, mp*128:(mp+1)*128] . W1[slice, k]
// 256 blocks = 16 b x 16 m-slices; 256 threads = k. W1 loads coalesced
// (1024B per wave per m); sep reads are wave-uniform -> scalar loads.
// fp32 slice accumulation: slice error ~1e-5 vs 0.02 budget on y.
__global__ __launch_bounds__(256) void mlp1_kernel(
    const float* __restrict__ sep,
    const float* __restrict__ W1,
    float* __restrict__ partial)
{
    const int b  = blockIdx.x >> 4;
    const int mp = blockIdx.x & 15;
    const int k  = threadIdx.x;
    const float* sv = sep + b * 2048 + mp * 128;
    const float* w  = W1 + mp * 128 * 256 + k;
    float a0 = 0, a1 = 0, a2 = 0, a3 = 0;
#pragma unroll 8
    for (int m = 0; m < 128; m += 4) {
        a0 += sv[m]     * w[(m)     * 256];
        a1 += sv[m + 1] * w[(m + 1) * 256];
        a2 += sv[m + 2] * w[(m + 2) * 256];
        a3 += sv[m + 3] * w[(m + 3) * 256];
    }
    partial[blockIdx.x * 256 + k] = (a0 + a1) + (a2 + a3);
}

// MLP stage 2: h[k] = celu(sum_p partial + b1) in double; y = h.W2 + b2;
// out = exp(-y). 16 blocks x 256 threads, deterministic reduction.
__global__ __launch_bounds__(256) void mlp2_kernel(
    const float* __restrict__ partial,
    const float* __restrict__ b1,
    const float* __restrict__ W2,
    const float* __restrict__ b2,
    float* __restrict__ out)
{
    __shared__ double red[4];
    const int b = blockIdx.x;
    const int k = threadIdx.x;
    double s = 0;
#pragma unroll
    for (int p = 0; p < 16; p++)
        s += (double)partial[(b * 16 + p) * 256 + k];
    s += (double)b1[k];
    s = s >= 0.0 ? s : exp(s) - 1.0;          // celu
    double q = s * (double)W2[k];
    for (int off = 32; off >= 1; off >>= 1) q += __shfl_down(q, off);
    if ((k & 63) == 0) red[k >> 6] = q;
    __syncthreads();
    if (k == 0) {
        double y = ((red[0] + red[1]) + (red[2] + red[3])) + (double)b2[0];
        out[b] = (float)exp(-y);
    }
}

extern "C" void kernel_launch(void* const* d_in, const int* in_sizes, int n_in,
                              void* d_out, int out_size, void* d_ws, size_t ws_size,
                              hipStream_t stream) {
    const float* nn     = (const float*)d_in[0];
    const float* w_self = (const float*)d_in[1];
    const float* w_nbr  = (const float*)d_in[2];
    const float* W1     = (const float*)d_in[3];
    const float* b1     = (const float*)d_in[4];
    const float* W2     = (const float*)d_in[5];
    const float* b2     = (const float*)d_in[6];
    float* out = (float*)d_out;
    float* sep     = (float*)d_ws;                                  // 128 KB
    float* partial = (float*)((char*)d_ws + 16 * CCH * LSZ * sizeof(float)); // 256 KB

    hipMemsetAsync(sep, 0, 16 * CCH * LSZ * sizeof(float), stream);
    stencil_kernel<<<64 * 36, 256, 0, stream>>>(nn, w_self, w_nbr, sep);
    mlp1_kernel<<<256, 256, 0, stream>>>(sep, W1, partial);
    mlp2_kernel<<<16, 256, 0, stream>>>(partial, b1, W2, b2, out);
}